// Round 9
// baseline (249.529 us; speedup 1.0000x reference)
//
#include <hip/hip_runtime.h>

#define C_DIM 1000
#define WPC   3             // words per column: sp, sn, cnt interleaved
#define RSTR  3072          // row stride in words (3000 used, padded)
#define NRED  250           // reducer blocks (column quads)

typedef float f32x4 __attribute__((ext_vector_type(4)));
typedef int   i32x4 __attribute__((ext_vector_type(4)));

// Inline-asm 16B loads (R6): ordered volatile asm keeps all 8 loads in flight.
#define GLOAD(dst, addr) \
    asm volatile("global_load_dwordx4 %0, %1, off" : "=v"(dst) : "v"(addr))

// ---------------------------------------------------------------------------
// Fused kernel: streaming partial reduction + in-kernel grid handoff + reduce.
// Phase A (all blocks): stream contiguous row range, LDS-merge 4 groups,
//   store interleaved 3000-word partial to slice blockIdx; release-fence;
//   ticket++.
// Phase B (blocks 0..249): spin on ticket==gridDim (all blocks co-resident:
//   512 blocks x 16 waves = 32 waves/CU exactly); acquire-fence; reduce
//   column-quad j=blockIdx across S slices; atomicAdd scalar (L,V); last
//   reducer writes out[0].
// ctrl[0]=ticket1 ctrl[1]=ticket2 ctrl[2..3]=(L,V) floats — memset per launch.
//
// softplus(x)  = max(x,0)  + ln2 * log2(1 + 2^(-|x|*log2e))   (log2 term shared)
// Labels are {0,1}; counts pack as (n_pos | n_neg<<16).
// ---------------------------------------------------------------------------
__global__ __launch_bounds__(1024) void nrl_fused_kernel(
    const float* __restrict__ pred,
    const int*   __restrict__ labels,
    unsigned int* __restrict__ ws_data,   // [S][RSTR] words
    unsigned int* __restrict__ ctrl,
    float* __restrict__ out,
    int N, int S, int store_mode)
{
    const int g   = threadIdx.x >> 8;     // row-group 0..3
    const int tid = threadIdx.x & 255;    // lane-in-group

    __shared__ float        s_sp[4][1024];
    __shared__ float        s_sn[4][1024];
    __shared__ unsigned int s_ct[4][1024];

    const float NEG_LOG2E = -1.4426950408889634f;
    const float LN2       =  0.6931471805599453f;

    float l2p[4] = {0.f,0.f,0.f,0.f};
    float l2n[4] = {0.f,0.f,0.f,0.f};
    float lip[4] = {0.f,0.f,0.f,0.f};
    float lin[4] = {0.f,0.f,0.f,0.f};
    unsigned int cnt[4] = {0u,0u,0u,0u};

#define PROC(P, Y)                                                          \
    {                                                                       \
        _Pragma("unroll")                                                   \
        for (int j = 0; j < 4; ++j) {                                       \
            const float x  = (P)[j];                                        \
            const float u  = NEG_LOG2E * fabsf(x);                          \
            const float e2 = __builtin_amdgcn_exp2f(u);                     \
            const float l2 = __builtin_amdgcn_logf(1.0f + e2);              \
            const float r  = fmaxf(x, 0.0f);                                \
            const float rn = r - x; /* = max(-x,0) */                       \
            const bool isp = ((Y)[j] == 1);                                 \
            l2p[j] += isp ? l2 : 0.0f;                                      \
            l2n[j] += isp ? 0.0f : l2;                                      \
            lip[j] += isp ? rn : 0.0f;                                      \
            lin[j] += isp ? 0.0f : r;                                       \
            cnt[j] += isp ? 1u : 0x10000u;                                  \
        }                                                                   \
    }

    if (tid < 250) {
        const int c0 = tid * 4;

        // balanced contiguous partition of N rows over (gridDim*4) streams
        const int nstreams = gridDim.x << 2;
        const int sid = (blockIdx.x << 2) | g;
        const int q   = N / nstreams;
        const int rem = N % nstreams;
        const int r0  = sid * q + (sid < rem ? sid : rem);
        const int r1  = r0 + q + (sid < rem ? 1 : 0);

        int r = r0;
        for (; r + 4 <= r1; r += 4) {
            const size_t b0 = (size_t)r * C_DIM + c0;           // rows r..r+3
            const size_t b1 = b0 + C_DIM;
            const size_t b2 = b0 + 2 * C_DIM;
            const size_t b3 = b0 + 3 * C_DIM;

            f32x4 p0, p1, p2, p3;
            i32x4 y0, y1, y2, y3;
            GLOAD(p0, pred + b0);   GLOAD(y0, labels + b0);
            GLOAD(p1, pred + b1);   GLOAD(y1, labels + b1);
            GLOAD(p2, pred + b2);   GLOAD(y2, labels + b2);
            GLOAD(p3, pred + b3);   GLOAD(y3, labels + b3);
            asm volatile("s_waitcnt vmcnt(0)" ::: "memory");
            __builtin_amdgcn_sched_barrier(0);
            PROC(p0, y0) PROC(p1, y1) PROC(p2, y2) PROC(p3, y3)
        }
        for (; r < r1; ++r) {
            const size_t b0 = (size_t)r * C_DIM + c0;
            const f32x4 p0 = *reinterpret_cast<const f32x4*>(pred + b0);
            const i32x4 y0 = *reinterpret_cast<const i32x4*>(labels + b0);
            PROC(p0, y0)
        }
#undef PROC

        float4 vp, vn; uint4 vc;
        vp.x = l2p[0]*LN2 + lip[0]; vp.y = l2p[1]*LN2 + lip[1];
        vp.z = l2p[2]*LN2 + lip[2]; vp.w = l2p[3]*LN2 + lip[3];
        vn.x = l2n[0]*LN2 + lin[0]; vn.y = l2n[1]*LN2 + lin[1];
        vn.z = l2n[2]*LN2 + lin[2]; vn.w = l2n[3]*LN2 + lin[3];
        vc.x = cnt[0]; vc.y = cnt[1]; vc.z = cnt[2]; vc.w = cnt[3];
        *reinterpret_cast<float4*>(&s_sp[g][c0]) = vp;
        *reinterpret_cast<float4*>(&s_sn[g][c0]) = vn;
        *reinterpret_cast<uint4*>(&s_ct[g][c0])  = vc;
    }
    __syncthreads();

    // merge 4 groups; result into registers
    const int t = threadIdx.x;
    {
        float sp = 0.f, sn = 0.f;
        unsigned int c = 0u;
        if (t < C_DIM) {
            sp = s_sp[0][t] + s_sp[1][t] + s_sp[2][t] + s_sp[3][t];
            sn = s_sn[0][t] + s_sn[1][t] + s_sn[2][t] + s_sn[3][t];
            c  = s_ct[0][t] + s_ct[1][t] + s_ct[2][t] + s_ct[3][t];
        }
        __syncthreads();   // reads of s_* done before staging overwrites

        unsigned int* stage = reinterpret_cast<unsigned int*>(&s_sp[0][0]);
        if (t < C_DIM) {
            stage[3*t + 0] = __float_as_uint(sp);
            stage[3*t + 1] = __float_as_uint(sn);
            stage[3*t + 2] = c;
        }
        __syncthreads();

        if (store_mode) {
            unsigned int* dst = ws_data + (size_t)blockIdx.x * RSTR;
            for (int w = t; w < WPC * C_DIM; w += 1024)   // coalesced
                dst[w] = stage[w];
        } else {
            unsigned int* dst = ws_data + (size_t)(blockIdx.x % S) * RSTR;
            for (int w = t; w < WPC * C_DIM; w += 1024) {
                if ((w % 3) == 2) atomicAdd(&dst[w], stage[w]);
                else              atomicAdd((float*)&dst[w], __uint_as_float(stage[w]));
            }
        }
    }

    // ---- release: partials visible, then ticket ----
    __threadfence();
    __syncthreads();
    if (t == 0) atomicAdd(&ctrl[0], 1u);

    if (blockIdx.x >= NRED) return;

    // ---- Phase B: reducers spin until all blocks stored ----
    if (t == 0) {
        const unsigned int total = gridDim.x;
        unsigned int cur;
        do {
            __builtin_amdgcn_s_sleep(2);
            cur = atomicAdd(&ctrl[0], 0u);
        } while (cur < total);
        __threadfence();   // acquire
    }
    __syncthreads();

    const int j = blockIdx.x;           // column quad 0..249
    float sp[4] = {0.f,0.f,0.f,0.f};
    float sn[4] = {0.f,0.f,0.f,0.f};
    unsigned int ct[4] = {0u,0u,0u,0u};

    for (int s = t; s < S; s += 1024) {
        const unsigned int* row = ws_data + (size_t)s * RSTR + j * 12;
        const uint4 A = *reinterpret_cast<const uint4*>(row + 0);
        const uint4 B = *reinterpret_cast<const uint4*>(row + 4);
        const uint4 C = *reinterpret_cast<const uint4*>(row + 8);
        sp[0] += __uint_as_float(A.x); sn[0] += __uint_as_float(A.y); ct[0] += A.z;
        sp[1] += __uint_as_float(A.w); sn[1] += __uint_as_float(B.x); ct[1] += B.y;
        sp[2] += __uint_as_float(B.z); sn[2] += __uint_as_float(B.w); ct[2] += C.x;
        sp[3] += __uint_as_float(C.y); sn[3] += __uint_as_float(C.z); ct[3] += C.w;
    }

#pragma unroll
    for (int off = 32; off > 0; off >>= 1) {
#pragma unroll
        for (int q = 0; q < 4; ++q) {
            sp[q] += __shfl_down(sp[q], off);
            sn[q] += __shfl_down(sn[q], off);
            ct[q] += __shfl_down(ct[q], off);
        }
    }

    __shared__ float        r_sp[16][4], r_sn[16][4];
    __shared__ unsigned int r_ct[16][4];
    const int wid  = t >> 6;
    const int lane = t & 63;
    if (lane == 0) {
#pragma unroll
        for (int q = 0; q < 4; ++q) { r_sp[wid][q]=sp[q]; r_sn[wid][q]=sn[q]; r_ct[wid][q]=ct[q]; }
    }
    __syncthreads();

    if (t == 0) {
        float L = 0.f, V = 0.f;
        float* LVf = (float*)&ctrl[2];
#pragma unroll
        for (int q = 0; q < 4; ++q) {
            float tsp = 0.f, tsn = 0.f; unsigned int tct = 0u;
#pragma unroll
            for (int w = 0; w < 16; ++w) { tsp+=r_sp[w][q]; tsn+=r_sn[w][q]; tct+=r_ct[w][q]; }
            const float np = (float)(tct & 0xFFFFu);
            const float nn = (float)(tct >> 16);
            const bool valid = (np > 0.f) && (nn > 0.f);
            const float l = tsp / fmaxf(np, 1.f) + tsn / fmaxf(nn, 1.f);
            L += valid ? l   : 0.f;
            V += valid ? 1.f : 0.f;
        }
        atomicAdd(&LVf[0], L);
        atomicAdd(&LVf[1], V);
        const unsigned int old = atomicAdd(&ctrl[1], 1u);
        if (old == NRED - 1) {
            const float Lt = atomicAdd(&LVf[0], 0.0f);   // coherent reads
            const float Vt = atomicAdd(&LVf[1], 0.0f);
            out[0] = Lt / fmaxf(Vt, 1.0f);
        }
    }
}

// ---------------------------------------------------------------------------
extern "C" void kernel_launch(void* const* d_in, const int* in_sizes, int n_in,
                              void* d_out, int out_size, void* d_ws, size_t ws_size,
                              hipStream_t stream)
{
    const float* pred   = (const float*)d_in[0];
    const int*   labels = (const int*)d_in[1];
    const int N = in_sizes[0] / C_DIM;

    const size_t tail      = 64;                               // ctrl words
    const size_t bytes512  = (size_t)512 * RSTR * 4 + tail;    // ~6.30 MB
    const size_t bytes256  = (size_t)256 * RSTR * 4 + tail;    // ~3.15 MB

    int store_mode, S, nblk;
    if (ws_size >= bytes512) {
        store_mode = 1; S = 512; nblk = 512;   // 2 blocks/CU = 32 waves/CU, all resident
    } else if (ws_size >= bytes256) {
        store_mode = 1; S = 256; nblk = 256;
    } else {
        store_mode = 0; nblk = 256;
        S = (int)((ws_size - tail) / ((size_t)RSTR * 4));
        if (S > 64) S = 64;
        if (S < 1)  S = 1;
    }

    unsigned int* ws_data = (unsigned int*)d_ws;
    unsigned int* ctrl    = ws_data + (size_t)S * RSTR;

    if (store_mode) {
        hipMemsetAsync(ctrl, 0, 16, stream);                       // tickets + LV
    } else {
        hipMemsetAsync(ws_data, 0, (size_t)S * RSTR * 4 + 16, stream);
    }

    nrl_fused_kernel<<<nblk, 1024, 0, stream>>>(pred, labels, ws_data, ctrl,
                                                (float*)d_out, N, S, store_mode);
}

// Round 10
// 113.293 us; speedup vs baseline: 2.2025x; 2.2025x over previous
//
#include <hip/hip_runtime.h>

#define C_DIM 1000
#define WPC   3             // words per column: sp, sn, cnt interleaved
#define RSTR  3072          // row stride in words (3000 used, padded)
#define NRED  250           // reducer blocks (column quads)

typedef float f32x4 __attribute__((ext_vector_type(4)));
typedef int   i32x4 __attribute__((ext_vector_type(4)));

// Inline-asm 16B loads (R6): ordered volatile asm keeps all 8 loads in flight.
#define GLOAD(dst, addr) \
    asm volatile("global_load_dwordx4 %0, %1, off" : "=v"(dst) : "v"(addr))

// ---------------------------------------------------------------------------
// Fused kernel: streaming partial reduction + in-kernel grid handoff + reduce.
// R10 change vs R9: the Phase-B spin polls with a READ-ONLY device-scope
// atomic load + s_sleep backoff. R9 polled with atomicAdd(,0) — an RMW —
// and 250 spinning blocks formed a serialized RMW convoy on ctrl[0] that the
// 512 release increments had to queue behind (+240 us). Reads don't convoy.
//
// Phase A (all blocks): stream contiguous row range, LDS-merge 4 groups,
//   store interleaved 3000-word partial to slice blockIdx; release-fence;
//   ticket++.  (512 blocks x 1024 thr = exactly 2 blocks/CU, all co-resident
//   — proven by R9 completing rather than deadlocking.)
// Phase B (blocks 0..249): spin-read ticket==gridDim; acquire-fence; reduce
//   column-quad j=blockIdx across S slices; atomicAdd scalar (L,V); last
//   reducer writes out[0].
// ctrl[0]=ticket1 ctrl[1]=ticket2 ctrl[2..3]=(L,V) floats — memset per launch.
//
// softplus(x)  = max(x,0)  + ln2 * log2(1 + 2^(-|x|*log2e))   (log2 term shared)
// Labels are {0,1}; counts pack as (n_pos | n_neg<<16).
// ---------------------------------------------------------------------------
__global__ __launch_bounds__(1024) void nrl_fused_kernel(
    const float* __restrict__ pred,
    const int*   __restrict__ labels,
    unsigned int* __restrict__ ws_data,   // [S][RSTR] words
    unsigned int* __restrict__ ctrl,
    float* __restrict__ out,
    int N, int S, int store_mode)
{
    const int g   = threadIdx.x >> 8;     // row-group 0..3
    const int tid = threadIdx.x & 255;    // lane-in-group

    __shared__ float        s_sp[4][1024];
    __shared__ float        s_sn[4][1024];
    __shared__ unsigned int s_ct[4][1024];

    const float NEG_LOG2E = -1.4426950408889634f;
    const float LN2       =  0.6931471805599453f;

    float l2p[4] = {0.f,0.f,0.f,0.f};
    float l2n[4] = {0.f,0.f,0.f,0.f};
    float lip[4] = {0.f,0.f,0.f,0.f};
    float lin[4] = {0.f,0.f,0.f,0.f};
    unsigned int cnt[4] = {0u,0u,0u,0u};

#define PROC(P, Y)                                                          \
    {                                                                       \
        _Pragma("unroll")                                                   \
        for (int j = 0; j < 4; ++j) {                                       \
            const float x  = (P)[j];                                        \
            const float u  = NEG_LOG2E * fabsf(x);                          \
            const float e2 = __builtin_amdgcn_exp2f(u);                     \
            const float l2 = __builtin_amdgcn_logf(1.0f + e2);              \
            const float r  = fmaxf(x, 0.0f);                                \
            const float rn = r - x; /* = max(-x,0) */                       \
            const bool isp = ((Y)[j] == 1);                                 \
            l2p[j] += isp ? l2 : 0.0f;                                      \
            l2n[j] += isp ? 0.0f : l2;                                      \
            lip[j] += isp ? rn : 0.0f;                                      \
            lin[j] += isp ? 0.0f : r;                                       \
            cnt[j] += isp ? 1u : 0x10000u;                                  \
        }                                                                   \
    }

    if (tid < 250) {
        const int c0 = tid * 4;

        // balanced contiguous partition of N rows over (gridDim*4) streams
        const int nstreams = gridDim.x << 2;
        const int sid = (blockIdx.x << 2) | g;
        const int q   = N / nstreams;
        const int rem = N % nstreams;
        const int r0  = sid * q + (sid < rem ? sid : rem);
        const int r1  = r0 + q + (sid < rem ? 1 : 0);

        int r = r0;
        for (; r + 4 <= r1; r += 4) {
            const size_t b0 = (size_t)r * C_DIM + c0;           // rows r..r+3
            const size_t b1 = b0 + C_DIM;
            const size_t b2 = b0 + 2 * C_DIM;
            const size_t b3 = b0 + 3 * C_DIM;

            f32x4 p0, p1, p2, p3;
            i32x4 y0, y1, y2, y3;
            GLOAD(p0, pred + b0);   GLOAD(y0, labels + b0);
            GLOAD(p1, pred + b1);   GLOAD(y1, labels + b1);
            GLOAD(p2, pred + b2);   GLOAD(y2, labels + b2);
            GLOAD(p3, pred + b3);   GLOAD(y3, labels + b3);
            asm volatile("s_waitcnt vmcnt(0)" ::: "memory");
            __builtin_amdgcn_sched_barrier(0);
            PROC(p0, y0) PROC(p1, y1) PROC(p2, y2) PROC(p3, y3)
        }
        for (; r < r1; ++r) {
            const size_t b0 = (size_t)r * C_DIM + c0;
            const f32x4 p0 = *reinterpret_cast<const f32x4*>(pred + b0);
            const i32x4 y0 = *reinterpret_cast<const i32x4*>(labels + b0);
            PROC(p0, y0)
        }
#undef PROC

        float4 vp, vn; uint4 vc;
        vp.x = l2p[0]*LN2 + lip[0]; vp.y = l2p[1]*LN2 + lip[1];
        vp.z = l2p[2]*LN2 + lip[2]; vp.w = l2p[3]*LN2 + lip[3];
        vn.x = l2n[0]*LN2 + lin[0]; vn.y = l2n[1]*LN2 + lin[1];
        vn.z = l2n[2]*LN2 + lin[2]; vn.w = l2n[3]*LN2 + lin[3];
        vc.x = cnt[0]; vc.y = cnt[1]; vc.z = cnt[2]; vc.w = cnt[3];
        *reinterpret_cast<float4*>(&s_sp[g][c0]) = vp;
        *reinterpret_cast<float4*>(&s_sn[g][c0]) = vn;
        *reinterpret_cast<uint4*>(&s_ct[g][c0])  = vc;
    }
    __syncthreads();

    // merge 4 groups; stage interleaved; store slice
    const int t = threadIdx.x;
    {
        float sp = 0.f, sn = 0.f;
        unsigned int c = 0u;
        if (t < C_DIM) {
            sp = s_sp[0][t] + s_sp[1][t] + s_sp[2][t] + s_sp[3][t];
            sn = s_sn[0][t] + s_sn[1][t] + s_sn[2][t] + s_sn[3][t];
            c  = s_ct[0][t] + s_ct[1][t] + s_ct[2][t] + s_ct[3][t];
        }
        __syncthreads();   // reads of s_* done before staging overwrites

        unsigned int* stage = reinterpret_cast<unsigned int*>(&s_sp[0][0]);
        if (t < C_DIM) {
            stage[3*t + 0] = __float_as_uint(sp);
            stage[3*t + 1] = __float_as_uint(sn);
            stage[3*t + 2] = c;
        }
        __syncthreads();

        if (store_mode) {
            unsigned int* dst = ws_data + (size_t)blockIdx.x * RSTR;
            for (int w = t; w < WPC * C_DIM; w += 1024)   // coalesced
                dst[w] = stage[w];
        } else {
            unsigned int* dst = ws_data + (size_t)(blockIdx.x % S) * RSTR;
            for (int w = t; w < WPC * C_DIM; w += 1024) {
                if ((w % 3) == 2) atomicAdd(&dst[w], stage[w]);
                else              atomicAdd((float*)&dst[w], __uint_as_float(stage[w]));
            }
        }
    }

    // ---- release: partials visible, then ticket (R7-validated pattern) ----
    __syncthreads();
    if (t == 0) {
        __threadfence();
        atomicAdd(&ctrl[0], 1u);
    }

    if (blockIdx.x >= NRED) return;

    // ---- Phase B: reducers spin (READ-ONLY poll + backoff) ----
    if (t == 0) {
        const unsigned int total = gridDim.x;
        while (__hip_atomic_load(&ctrl[0], __ATOMIC_RELAXED,
                                 __HIP_MEMORY_SCOPE_AGENT) < total) {
            __builtin_amdgcn_s_sleep(8);
        }
        __threadfence();   // acquire
    }
    __syncthreads();

    const int j = blockIdx.x;           // column quad 0..249
    float sp[4] = {0.f,0.f,0.f,0.f};
    float sn[4] = {0.f,0.f,0.f,0.f};
    unsigned int ct[4] = {0u,0u,0u,0u};

    for (int s = t; s < S; s += 1024) {
        const unsigned int* row = ws_data + (size_t)s * RSTR + j * 12;
        const uint4 A = *reinterpret_cast<const uint4*>(row + 0);
        const uint4 B = *reinterpret_cast<const uint4*>(row + 4);
        const uint4 C = *reinterpret_cast<const uint4*>(row + 8);
        sp[0] += __uint_as_float(A.x); sn[0] += __uint_as_float(A.y); ct[0] += A.z;
        sp[1] += __uint_as_float(A.w); sn[1] += __uint_as_float(B.x); ct[1] += B.y;
        sp[2] += __uint_as_float(B.z); sn[2] += __uint_as_float(B.w); ct[2] += C.x;
        sp[3] += __uint_as_float(C.y); sn[3] += __uint_as_float(C.z); ct[3] += C.w;
    }

#pragma unroll
    for (int off = 32; off > 0; off >>= 1) {
#pragma unroll
        for (int q = 0; q < 4; ++q) {
            sp[q] += __shfl_down(sp[q], off);
            sn[q] += __shfl_down(sn[q], off);
            ct[q] += __shfl_down(ct[q], off);
        }
    }

    __shared__ float        r_sp[16][4], r_sn[16][4];
    __shared__ unsigned int r_ct[16][4];
    const int wid  = t >> 6;
    const int lane = t & 63;
    if (lane == 0) {
#pragma unroll
        for (int q = 0; q < 4; ++q) { r_sp[wid][q]=sp[q]; r_sn[wid][q]=sn[q]; r_ct[wid][q]=ct[q]; }
    }
    __syncthreads();

    if (t == 0) {
        float L = 0.f, V = 0.f;
        float* LVf = (float*)&ctrl[2];
#pragma unroll
        for (int q = 0; q < 4; ++q) {
            float tsp = 0.f, tsn = 0.f; unsigned int tct = 0u;
#pragma unroll
            for (int w = 0; w < 16; ++w) { tsp+=r_sp[w][q]; tsn+=r_sn[w][q]; tct+=r_ct[w][q]; }
            const float np = (float)(tct & 0xFFFFu);
            const float nn = (float)(tct >> 16);
            const bool valid = (np > 0.f) && (nn > 0.f);
            const float l = tsp / fmaxf(np, 1.f) + tsn / fmaxf(nn, 1.f);
            L += valid ? l   : 0.f;
            V += valid ? 1.f : 0.f;
        }
        atomicAdd(&LVf[0], L);
        atomicAdd(&LVf[1], V);
        const unsigned int old = atomicAdd(&ctrl[1], 1u);
        if (old == NRED - 1) {
            const float Lt = atomicAdd(&LVf[0], 0.0f);   // coherent reads
            const float Vt = atomicAdd(&LVf[1], 0.0f);
            out[0] = Lt / fmaxf(Vt, 1.0f);
        }
    }
}

// ---------------------------------------------------------------------------
extern "C" void kernel_launch(void* const* d_in, const int* in_sizes, int n_in,
                              void* d_out, int out_size, void* d_ws, size_t ws_size,
                              hipStream_t stream)
{
    const float* pred   = (const float*)d_in[0];
    const int*   labels = (const int*)d_in[1];
    const int N = in_sizes[0] / C_DIM;

    const size_t tail      = 64;                               // ctrl words
    const size_t bytes512  = (size_t)512 * RSTR * 4 + tail;    // ~6.30 MB
    const size_t bytes256  = (size_t)256 * RSTR * 4 + tail;    // ~3.15 MB

    int store_mode, S, nblk;
    if (ws_size >= bytes512) {
        store_mode = 1; S = 512; nblk = 512;   // 2 blocks/CU = 32 waves/CU, all resident
    } else if (ws_size >= bytes256) {
        store_mode = 1; S = 256; nblk = 256;
    } else {
        store_mode = 0; nblk = 256;
        S = (int)((ws_size - tail) / ((size_t)RSTR * 4));
        if (S > 64) S = 64;
        if (S < 1)  S = 1;
    }

    unsigned int* ws_data = (unsigned int*)d_ws;
    unsigned int* ctrl    = ws_data + (size_t)S * RSTR;

    if (store_mode) {
        hipMemsetAsync(ctrl, 0, 16, stream);                       // tickets + LV
    } else {
        hipMemsetAsync(ws_data, 0, (size_t)S * RSTR * 4 + 16, stream);
    }

    nrl_fused_kernel<<<nblk, 1024, 0, stream>>>(pred, labels, ws_data, ctrl,
                                                (float*)d_out, N, S, store_mode);
}

// Round 11
// 55.561 us; speedup vs baseline: 4.4911x; 2.0391x over previous
//
#include <hip/hip_runtime.h>

#define C_DIM 1000
#define WPC   3             // words per column: sp, sn, cnt interleaved
#define RSTR  3072          // row stride in words (3000 used, padded)
#define NRED  250           // reducer blocks (column quads)

typedef float f32x4 __attribute__((ext_vector_type(4)));
typedef int   i32x4 __attribute__((ext_vector_type(4)));

// Inline-asm 16B loads (R6): ordered volatile asm keeps all 8 loads in flight.
#define GLOAD(dst, addr) \
    asm volatile("global_load_dwordx4 %0, %1, off" : "=v"(dst) : "v"(addr))

// ---------------------------------------------------------------------------
// Kernel 1 (R8-proven, byte-identical): streaming partial reduction.
// Contiguous stream partition: stream s = blockIdx*4 + g owns rows
// [s*q .. s*q+q) contiguously, read as 4-consecutive-row chunks; 8 asm loads
// in flight per iteration; LDS-merge of 4 groups; interleaved 3000-word
// partial stored to slice blockIdx (coalesced, no atomics).
// Block 0 thread 0 zeroes kernel2's ticket (safe: prior kernel2 finished).
//
// softplus(x)  = max(x,0)  + ln2 * log2(1 + 2^(-|x|*log2e))   (log2 term shared)
// Labels are {0,1}; counts pack as (n_pos | n_neg<<16).
// ---------------------------------------------------------------------------
__global__ __launch_bounds__(1024) void nrl_partial_kernel(
    const float* __restrict__ pred,
    const int*   __restrict__ labels,
    unsigned int* __restrict__ ws_data,   // [S][RSTR] words
    unsigned int* __restrict__ ticket,
    int N, int S, int store_mode)
{
    const int g   = threadIdx.x >> 8;     // row-group 0..3
    const int tid = threadIdx.x & 255;    // lane-in-group

    if (blockIdx.x == 0 && threadIdx.x == 0) atomicExch(ticket, 0u);

    __shared__ float        s_sp[4][1024];
    __shared__ float        s_sn[4][1024];
    __shared__ unsigned int s_ct[4][1024];

    const float NEG_LOG2E = -1.4426950408889634f;
    const float LN2       =  0.6931471805599453f;

    float l2p[4] = {0.f,0.f,0.f,0.f};
    float l2n[4] = {0.f,0.f,0.f,0.f};
    float lip[4] = {0.f,0.f,0.f,0.f};
    float lin[4] = {0.f,0.f,0.f,0.f};
    unsigned int cnt[4] = {0u,0u,0u,0u};

#define PROC(P, Y)                                                          \
    {                                                                       \
        _Pragma("unroll")                                                   \
        for (int j = 0; j < 4; ++j) {                                       \
            const float x  = (P)[j];                                        \
            const float u  = NEG_LOG2E * fabsf(x);                          \
            const float e2 = __builtin_amdgcn_exp2f(u);                     \
            const float l2 = __builtin_amdgcn_logf(1.0f + e2);              \
            const float r  = fmaxf(x, 0.0f);                                \
            const float rn = r - x; /* = max(-x,0) */                       \
            const bool isp = ((Y)[j] == 1);                                 \
            l2p[j] += isp ? l2 : 0.0f;                                      \
            l2n[j] += isp ? 0.0f : l2;                                      \
            lip[j] += isp ? rn : 0.0f;                                      \
            lin[j] += isp ? 0.0f : r;                                       \
            cnt[j] += isp ? 1u : 0x10000u;                                  \
        }                                                                   \
    }

    if (tid < 250) {
        const int c0 = tid * 4;

        // balanced contiguous partition of N rows over (gridDim*4) streams
        const int nstreams = gridDim.x << 2;
        const int sid = (blockIdx.x << 2) | g;
        const int q   = N / nstreams;
        const int rem = N % nstreams;
        const int r0  = sid * q + (sid < rem ? sid : rem);
        const int r1  = r0 + q + (sid < rem ? 1 : 0);

        int r = r0;
        for (; r + 4 <= r1; r += 4) {
            const size_t b0 = (size_t)r * C_DIM + c0;           // rows r..r+3
            const size_t b1 = b0 + C_DIM;
            const size_t b2 = b0 + 2 * C_DIM;
            const size_t b3 = b0 + 3 * C_DIM;

            f32x4 p0, p1, p2, p3;
            i32x4 y0, y1, y2, y3;
            GLOAD(p0, pred + b0);   GLOAD(y0, labels + b0);
            GLOAD(p1, pred + b1);   GLOAD(y1, labels + b1);
            GLOAD(p2, pred + b2);   GLOAD(y2, labels + b2);
            GLOAD(p3, pred + b3);   GLOAD(y3, labels + b3);
            asm volatile("s_waitcnt vmcnt(0)" ::: "memory");
            __builtin_amdgcn_sched_barrier(0);
            PROC(p0, y0) PROC(p1, y1) PROC(p2, y2) PROC(p3, y3)
        }
        for (; r < r1; ++r) {
            const size_t b0 = (size_t)r * C_DIM + c0;
            const f32x4 p0 = *reinterpret_cast<const f32x4*>(pred + b0);
            const i32x4 y0 = *reinterpret_cast<const i32x4*>(labels + b0);
            PROC(p0, y0)
        }
#undef PROC

        float4 vp, vn; uint4 vc;
        vp.x = l2p[0]*LN2 + lip[0]; vp.y = l2p[1]*LN2 + lip[1];
        vp.z = l2p[2]*LN2 + lip[2]; vp.w = l2p[3]*LN2 + lip[3];
        vn.x = l2n[0]*LN2 + lin[0]; vn.y = l2n[1]*LN2 + lin[1];
        vn.z = l2n[2]*LN2 + lin[2]; vn.w = l2n[3]*LN2 + lin[3];
        vc.x = cnt[0]; vc.y = cnt[1]; vc.z = cnt[2]; vc.w = cnt[3];
        *reinterpret_cast<float4*>(&s_sp[g][c0]) = vp;
        *reinterpret_cast<float4*>(&s_sn[g][c0]) = vn;
        *reinterpret_cast<uint4*>(&s_ct[g][c0])  = vc;
    }
    __syncthreads();

    // merge 4 groups; result into registers
    const int t = threadIdx.x;
    float sp = 0.f, sn = 0.f;
    unsigned int c = 0u;
    if (t < C_DIM) {
        sp = s_sp[0][t] + s_sp[1][t] + s_sp[2][t] + s_sp[3][t];
        sn = s_sn[0][t] + s_sn[1][t] + s_sn[2][t] + s_sn[3][t];
        c  = s_ct[0][t] + s_ct[1][t] + s_ct[2][t] + s_ct[3][t];
    }
    __syncthreads();   // all reads of s_* done before staging overwrites

    // stage interleaved [3t]=sp [3t+1]=sn [3t+2]=cnt (stride-3: conflict-free)
    unsigned int* stage = reinterpret_cast<unsigned int*>(&s_sp[0][0]);
    if (t < C_DIM) {
        stage[3*t + 0] = __float_as_uint(sp);
        stage[3*t + 1] = __float_as_uint(sn);
        stage[3*t + 2] = c;
    }
    __syncthreads();

    if (store_mode) {
        unsigned int* dst = ws_data + (size_t)blockIdx.x * RSTR;
        for (int w = threadIdx.x; w < WPC * C_DIM; w += 1024)   // coalesced
            dst[w] = stage[w];
    } else {
        unsigned int* dst = ws_data + (size_t)(blockIdx.x % S) * RSTR;
        for (int w = threadIdx.x; w < WPC * C_DIM; w += 1024) {
            if ((w % 3) == 2) atomicAdd(&dst[w], stage[w]);
            else              atomicAdd((float*)&dst[w], __uint_as_float(stage[w]));
        }
    }
}

// ---------------------------------------------------------------------------
// Kernel 2 (R11 tweak: 1024 threads -> S<=1024 gathered in ONE sweep instead
// of a 2-iteration latency chain). Block j reduces column-quad j across S
// slices, writes its (L,V) partial, takes a ticket; last block reduces the
// 250 partials into out[0].
// ---------------------------------------------------------------------------
__global__ __launch_bounds__(1024) void nrl_reduce_kernel(
    const unsigned int* __restrict__ ws_data,
    float*        __restrict__ pb,      // [250][2] partial L,V
    unsigned int* __restrict__ ticket,
    float* __restrict__ out, int S)
{
    const int j = blockIdx.x;           // column quad 0..249
    const int t = threadIdx.x;
    float sp[4] = {0.f,0.f,0.f,0.f};
    float sn[4] = {0.f,0.f,0.f,0.f};
    unsigned int ct[4] = {0u,0u,0u,0u};

    for (int s = t; s < S; s += 1024) {   // single iteration when S<=1024
        const unsigned int* row = ws_data + (size_t)s * RSTR + j * 12;
        const uint4 A = *reinterpret_cast<const uint4*>(row + 0);
        const uint4 B = *reinterpret_cast<const uint4*>(row + 4);
        const uint4 C = *reinterpret_cast<const uint4*>(row + 8);
        sp[0] += __uint_as_float(A.x); sn[0] += __uint_as_float(A.y); ct[0] += A.z;
        sp[1] += __uint_as_float(A.w); sn[1] += __uint_as_float(B.x); ct[1] += B.y;
        sp[2] += __uint_as_float(B.z); sn[2] += __uint_as_float(B.w); ct[2] += C.x;
        sp[3] += __uint_as_float(C.y); sn[3] += __uint_as_float(C.z); ct[3] += C.w;
    }

#pragma unroll
    for (int off = 32; off > 0; off >>= 1) {
#pragma unroll
        for (int q = 0; q < 4; ++q) {
            sp[q] += __shfl_down(sp[q], off);
            sn[q] += __shfl_down(sn[q], off);
            ct[q] += __shfl_down(ct[q], off);
        }
    }

    __shared__ float        w_sp[16][4], w_sn[16][4];
    __shared__ unsigned int w_ct[16][4];
    const int wid  = t >> 6;
    const int lane = t & 63;
    if (lane == 0) {
#pragma unroll
        for (int q = 0; q < 4; ++q) { w_sp[wid][q]=sp[q]; w_sn[wid][q]=sn[q]; w_ct[wid][q]=ct[q]; }
    }
    __syncthreads();

    __shared__ int s_last;
    if (t == 0) {
        float L = 0.f, V = 0.f;
#pragma unroll
        for (int q = 0; q < 4; ++q) {
            float tsp = 0.f, tsn = 0.f; unsigned int tct = 0u;
#pragma unroll
            for (int w = 0; w < 16; ++w) { tsp+=w_sp[w][q]; tsn+=w_sn[w][q]; tct+=w_ct[w][q]; }
            const float np = (float)(tct & 0xFFFFu);
            const float nn = (float)(tct >> 16);
            const bool valid = (np > 0.f) && (nn > 0.f);
            const float l = tsp / fmaxf(np, 1.f) + tsn / fmaxf(nn, 1.f);
            L += valid ? l   : 0.f;
            V += valid ? 1.f : 0.f;
        }
        atomicExch(&pb[2*j + 0], L);
        atomicExch(&pb[2*j + 1], V);
        __threadfence();
        const unsigned int old = atomicAdd(ticket, 1u);
        s_last = (old == (unsigned int)(gridDim.x - 1)) ? 1 : 0;
    }
    __syncthreads();

    if (s_last) {
        float l = 0.f, v = 0.f;
        if (t < 250) {
            l = atomicAdd(&pb[2*t + 0], 0.0f);   // coherent device-scope read
            v = atomicAdd(&pb[2*t + 1], 0.0f);
        }
#pragma unroll
        for (int off = 32; off > 0; off >>= 1) {
            l += __shfl_down(l, off);
            v += __shfl_down(v, off);
        }
        __shared__ float f_l[16], f_v[16];
        if (lane == 0) { f_l[wid] = l; f_v[wid] = v; }
        __syncthreads();
        if (t == 0) {
            float L = 0.f, V = 0.f;
#pragma unroll
            for (int w = 0; w < 16; ++w) { L += f_l[w]; V += f_v[w]; }
            out[0] = L / fmaxf(V, 1.0f);
        }
    }
}

// ---------------------------------------------------------------------------
extern "C" void kernel_launch(void* const* d_in, const int* in_sizes, int n_in,
                              void* d_out, int out_size, void* d_ws, size_t ws_size,
                              hipStream_t stream)
{
    const float* pred   = (const float*)d_in[0];
    const int*   labels = (const int*)d_in[1];
    const int N = in_sizes[0] / C_DIM;

    const size_t tail      = 500 * 4 + 64;                     // pb + ticket
    const size_t bytes512  = (size_t)512 * RSTR * 4 + tail;    // ~6.30 MB
    const size_t bytes256  = (size_t)256 * RSTR * 4 + tail;    // ~3.15 MB

    int store_mode, S, nblk;
    if (ws_size >= bytes512) {
        store_mode = 1; S = 512; nblk = 512;   // 2 blocks/CU
    } else if (ws_size >= bytes256) {
        store_mode = 1; S = 256; nblk = 256;
    } else {
        store_mode = 0; nblk = 256;
        S = (int)((ws_size - tail) / ((size_t)RSTR * 4));
        if (S > 64) S = 64;
        if (S < 1)  S = 1;
    }

    unsigned int* ws_data = (unsigned int*)d_ws;
    float*        pb      = (float*)(ws_data + (size_t)S * RSTR);
    unsigned int* ticket  = (unsigned int*)(pb + 500);

    if (!store_mode) {
        hipMemsetAsync(ws_data, 0, (size_t)S * RSTR * 4, stream);
    }

    nrl_partial_kernel<<<nblk, 1024, 0, stream>>>(pred, labels, ws_data, ticket,
                                                  N, S, store_mode);
    nrl_reduce_kernel<<<NRED, 1024, 0, stream>>>(ws_data, pb, ticket,
                                                 (float*)d_out, S);
}